// Round 2
// baseline (60.700 us; speedup 1.0000x reference)
//
#include <hip/hip_runtime.h>
#include <math.h>

// LIFNeuronFDE: fractional-order LIF with Grunwald-Letnikov memory.
//   v^{k+1} = h^beta * (I_k - v^k)/tau - sum_{j=0}^{k} c_{k+1-j} v^{(j)}
//   spike_k = sigmoid(scale * (v^{k+1} - V_th))
// Constants: tau=0.5, thresh=1.0, scale=5.0, beta=0.5, h=1.0 => h^beta=1, 1/tau=2.
// T=32, B=32, N=32768.
//
// R1 lesson: 2 elems/thread needed 128 VGPRs of fp64 history -> compiler
// spilled (VGPR_Count=72, ~4.4GB scratch traffic, latency-bound at 107us).
// Fix: ONE element per thread -> 32 doubles history = 64 VGPR, fits in
// registers. Arithmetic order/precision identical to R1 (fp64, ascending j),
// so output is bitwise identical (absmax margin is small: 0.0176/0.02).

#define T_STEPS 32
#define BN (32 * 32768)              // B*N = 1,048,576 elements

struct Coef { double c[T_STEPS + 1]; };

constexpr Coef make_coef() {
    Coef r{};
    r.c[0] = 1.0;
    double cur = 1.0;
    for (int j = 1; j <= T_STEPS; ++j) {
        cur *= (1.0 - 1.5 / (double)j);   // (1 - (1+beta)/j), beta=0.5
        r.c[j] = cur;
    }
    return r;
}

__global__ __launch_bounds__(256) void lif_fde_kernel(
    const float* __restrict__ I,
    const float* __restrict__ v0,
    float* __restrict__ out)
{
    constexpr Coef C = make_coef();

    const int idx = blockIdx.x * blockDim.x + threadIdx.x;   // [0, BN)

    double v = (double)v0[idx];

    double h[T_STEPS];   // full GL history in registers (64 VGPRs)

    #pragma unroll
    for (int k = 0; k < T_STEPS; ++k) {
        h[k] = v;

        // GL memory term: sum_{j=0}^{k} c[k+1-j] * v^{(j)}  (ascending j,
        // same order as R1 -> bitwise-identical output)
        double m = 0.0;
        #pragma unroll
        for (int j = 0; j <= k; ++j) {
            m = fma(C.c[k + 1 - j], h[j], m);
        }

        const float Ik = I[(size_t)k * BN + idx];

        // h^beta * (I - v)/tau - mem  with h^beta=1, 1/tau=2
        v = 2.0 * ((double)Ik - v) - m;

        // spike = sigmoid(5*(v - 1))
        const float a = (float)(-5.0 * (v - 1.0));
        out[(size_t)k * BN + idx] = 1.0f / (1.0f + __expf(a));
    }
}

extern "C" void kernel_launch(void* const* d_in, const int* in_sizes, int n_in,
                              void* d_out, int out_size, void* d_ws, size_t ws_size,
                              hipStream_t stream) {
    const float* I  = (const float*)d_in[0];   // (T, B, N) fp32
    const float* v0 = (const float*)d_in[1];   // (B, N) fp32
    float* out = (float*)d_out;                // (T, B, N) fp32

    dim3 block(256);
    dim3 grid(BN / 256);                       // 4096 blocks, exact fit
    lif_fde_kernel<<<grid, block, 0, stream>>>(I, v0, out);
}